// Round 5
// baseline (430.355 us; speedup 1.0000x reference)
//
#include <hip/hip_runtime.h>

#define N_NODES 50000
#define N_EDGES 800000
#define D 64
#define NUM_LAYERS 4
#define NUM_GRAPHS 128
#define N_ALL (2 * N_NODES)
#define E_ALL (2 * N_EDGES)
#define BSHIFT 9
#define NBUCK ((N_ALL + 511) / 512)     // 196 buckets of 512 dst ids
#define CHUNK 3072                      // edges per bin_scatter block (12/thread)
#define NCHUNK ((E_ALL + CHUNK - 1) / CHUNK)  // 521

typedef __attribute__((ext_vector_type(8))) short bf16x8;   // 8 bf16 (4 VGPRs)
typedef __attribute__((ext_vector_type(4))) float f32x4;    // MFMA accumulator

// ---------- bf16 helpers (RNE pack, shift unpack) ----------
__device__ __forceinline__ unsigned f2bf(float f) {
    unsigned u = __float_as_uint(f);
    return (u + 0x7FFFu + ((u >> 16) & 1u)) >> 16;
}
__device__ __forceinline__ float bflo(unsigned p) { return __uint_as_float(p << 16); }
__device__ __forceinline__ float bfhi(unsigned p) { return __uint_as_float(p & 0xFFFF0000u); }
__device__ __forceinline__ void acc8(float* a, uint4 v) {
    a[0] += bflo(v.x); a[1] += bfhi(v.x);
    a[2] += bflo(v.y); a[3] += bfhi(v.y);
    a[4] += bflo(v.z); a[5] += bfhi(v.z);
    a[6] += bflo(v.w); a[7] += bfhi(v.w);
}

// ---------- pre-pass: x fp32 -> bf16 (also zeroes bucketTotal, replacing memset) ----------
__global__ __launch_bounds__(256) void x_to_bf16(const float4* __restrict__ xf,
                                                 uint4* __restrict__ xb,
                                                 int* __restrict__ bucketTotal) {
    int t = threadIdx.x;
    if (blockIdx.x == 0 && t < NBUCK) bucketTotal[t] = 0;
    int idx = blockIdx.x * 256 + t;          // one uint4 (8 bf16) per thread
    if (idx < N_NODES * D / 8) {
        float4 v0 = xf[(size_t)idx * 2];
        float4 v1 = xf[(size_t)idx * 2 + 1];
        uint4 o;
        o.x = f2bf(v0.x) | (f2bf(v0.y) << 16);
        o.y = f2bf(v0.z) | (f2bf(v0.w) << 16);
        o.z = f2bf(v1.x) | (f2bf(v1.y) << 16);
        o.w = f2bf(v1.z) | (f2bf(v1.w) << 16);
        xb[idx] = o;
    }
}

// ---------- pass 0: coarse bucket totals (LDS histogram, tiny global flush) ----------
#define BC_BLOCKS 256
__global__ __launch_bounds__(256) void bucket_count(const int* __restrict__ dR,
                                                    const int* __restrict__ dX,
                                                    int* __restrict__ bucketTotal) {
    __shared__ int lc[NBUCK];
    int t = threadIdx.x;
    for (int j = t; j < NBUCK; j += 256) lc[j] = 0;
    __syncthreads();
    for (int e = blockIdx.x * 256 + t; e < N_EDGES; e += BC_BLOCKS * 256) {
        atomicAdd(&lc[dR[e] >> BSHIFT], 1);
        atomicAdd(&lc[(N_NODES + dX[e]) >> BSHIFT], 1);
    }
    __syncthreads();
    for (int j = t; j < NBUCK; j += 256) {
        int v = lc[j];
        if (v) atomicAdd(&bucketTotal[j], v);
    }
}

// ---------- pass 0b: scan 196 bucket totals (single block) ----------
__global__ __launch_bounds__(256) void bucket_scan(const int* __restrict__ bucketTotal,
                                                   int* __restrict__ bucketBase,
                                                   int* __restrict__ bucketCursor) {
    __shared__ int s[256];
    int t = threadIdx.x;
    int v = (t < NBUCK) ? bucketTotal[t] : 0;
    s[t] = v;
    __syncthreads();
    for (int off = 1; off < 256; off <<= 1) {
        int tv = (t >= off) ? s[t - off] : 0;
        __syncthreads();
        s[t] += tv;
        __syncthreads();
    }
    if (t < NBUCK) {
        int excl = s[t] - v;
        bucketBase[t] = excl;
        bucketCursor[t] = excl;
    }
    if (t == NBUCK - 1) bucketBase[NBUCK] = s[t];   // == E_ALL
}

// ---------- pass 1: bin u32 pairs (d_low9<<16 | src16) by bucket; coalesced runs ----------
__global__ __launch_bounds__(256) void bin_scatter(const int* __restrict__ sR,
                                                   const int* __restrict__ dR,
                                                   const int* __restrict__ sX,
                                                   const int* __restrict__ dX,
                                                   int* __restrict__ bucketCursor,
                                                   unsigned* __restrict__ pairs) {
    __shared__ unsigned lpair[CHUNK];
    __shared__ unsigned char lbuck[CHUNK];
    __shared__ int lcnt[NBUCK];
    __shared__ int lbase[NBUCK];
    __shared__ int gbase[NBUCK];
    __shared__ int sc[256];
    __shared__ int tot;
    int t = threadIdx.x;
    for (int j = t; j < NBUCK; j += 256) lcnt[j] = 0;
    __syncthreads();

    int base = blockIdx.x * CHUNK;
    unsigned myp[12];
    int myr[12], myb[12];
#pragma unroll
    for (int i = 0; i < 12; ++i) {
        int e = base + i * 256 + t;
        if (e < E_ALL) {
            bool isR = (e < N_EDGES);
            int d = isR ? dR[e] : (N_NODES + dX[e - N_EDGES]);
            int s = isR ? sR[e] : sX[e - N_EDGES];
            myp[i] = ((unsigned)(d & 511) << 16) | (unsigned)s;
            myb[i] = d >> BSHIFT;
            myr[i] = atomicAdd(&lcnt[myb[i]], 1);
        }
    }
    __syncthreads();

    int v = (t < NBUCK) ? lcnt[t] : 0;
    sc[t] = v;
    __syncthreads();
    for (int off = 1; off < 256; off <<= 1) {
        int tv = (t >= off) ? sc[t - off] : 0;
        __syncthreads();
        sc[t] += tv;
        __syncthreads();
    }
    if (t < NBUCK) {
        lbase[t] = sc[t] - v;
        if (v > 0) gbase[t] = atomicAdd(&bucketCursor[t], v);
    }
    if (t == NBUCK - 1) tot = sc[t];
    __syncthreads();

#pragma unroll
    for (int i = 0; i < 12; ++i) {
        int e = base + i * 256 + t;
        if (e < E_ALL) {
            int p = lbase[myb[i]] + myr[i];
            lpair[p] = myp[i];
            lbuck[p] = (unsigned char)myb[i];
        }
    }
    __syncthreads();

    int total = tot;
    for (int j = t; j < total; j += 256) {
        int b = lbuck[j];
        pairs[(size_t)gbase[b] + (j - lbase[b])] = lpair[j];
    }
}

// ---------- pass 2: per bucket -- degrees+rowptr in LDS, place col; writes coalesced ----------
__global__ __launch_bounds__(256) void bucket_place(const unsigned* __restrict__ pairs,
                                                    const int* __restrict__ bucketBase,
                                                    int* __restrict__ rowptr,
                                                    unsigned short* __restrict__ col) {
    __shared__ unsigned short scol[10240];
    __shared__ int ldeg[512];
    __shared__ int lcur[512];
    __shared__ int s1[256];
    int b = blockIdx.x;
    int d0 = b << BSHIFT;
    int nd = min(512, N_ALL - d0);
    int t = threadIdx.x;
    int base = bucketBase[b];
    int cnt = bucketBase[b + 1] - base;
    ldeg[t] = 0; ldeg[t + 256] = 0;
    __syncthreads();
    for (int i = t; i < cnt; i += 256) {
        int dl = pairs[(size_t)base + i] >> 16;
        atomicAdd(&ldeg[dl], 1);
    }
    __syncthreads();
    int v0 = ldeg[2 * t], v1 = ldeg[2 * t + 1];
    int pv = v0 + v1;
    s1[t] = pv;
    __syncthreads();
    for (int off = 1; off < 256; off <<= 1) {
        int tv = (t >= off) ? s1[t - off] : 0;
        __syncthreads();
        s1[t] += tv;
        __syncthreads();
    }
    int before = s1[t] - pv;
    lcur[2 * t] = before;
    lcur[2 * t + 1] = before + v0;
    if (2 * t < nd)     rowptr[d0 + 2 * t]     = base + before;
    if (2 * t + 1 < nd) rowptr[d0 + 2 * t + 1] = base + before + v0;
    if (b == NBUCK - 1 && t == 0) rowptr[N_ALL] = base + cnt;
    __syncthreads();
    for (int i = t; i < cnt; i += 256) {
        unsigned pr = pairs[(size_t)base + i];
        int dl = pr >> 16;
        int p = atomicAdd(&lcur[dl], 1);
        scol[p] = (unsigned short)(pr & 0xFFFFu);
    }
    __syncthreads();
    for (int i = t; i < cnt; i += 256) col[base + i] = scol[i];
}

// ---------- shared gather helper: a[8] += sum of neighbor rows (split-edge, unroll 8) ----------
__device__ __forceinline__ void gather_rows(const uint4* __restrict__ xb,
                                            const unsigned short* __restrict__ cp,
                                            int ch, int ln8, float* a) {
    int i = 0;
    for (; i + 8 <= ch; i += 8) {
        int s0 = cp[2 * i],      s1 = cp[2 * i + 2],  s2 = cp[2 * i + 4],  s3 = cp[2 * i + 6];
        int s4 = cp[2 * i + 8],  s5 = cp[2 * i + 10], s6 = cp[2 * i + 12], s7 = cp[2 * i + 14];
        uint4 v0 = xb[(size_t)s0 * 8 + ln8];
        uint4 v1 = xb[(size_t)s1 * 8 + ln8];
        uint4 v2 = xb[(size_t)s2 * 8 + ln8];
        uint4 v3 = xb[(size_t)s3 * 8 + ln8];
        uint4 v4 = xb[(size_t)s4 * 8 + ln8];
        uint4 v5 = xb[(size_t)s5 * 8 + ln8];
        uint4 v6 = xb[(size_t)s6 * 8 + ln8];
        uint4 v7 = xb[(size_t)s7 * 8 + ln8];
        acc8(a, v0); acc8(a, v1); acc8(a, v2); acc8(a, v3);
        acc8(a, v4); acc8(a, v5); acc8(a, v6); acc8(a, v7);
    }
    for (; i + 4 <= ch; i += 4) {
        int s0 = cp[2 * i], s1 = cp[2 * i + 2], s2 = cp[2 * i + 4], s3 = cp[2 * i + 6];
        uint4 v0 = xb[(size_t)s0 * 8 + ln8];
        uint4 v1 = xb[(size_t)s1 * 8 + ln8];
        uint4 v2 = xb[(size_t)s2 * 8 + ln8];
        uint4 v3 = xb[(size_t)s3 * 8 + ln8];
        acc8(a, v0); acc8(a, v1); acc8(a, v2); acc8(a, v3);
    }
    for (; i < ch; ++i) acc8(a, xb[(size_t)cp[2 * i] * 8 + ln8]);
}

// ---------- split-edge bf16 gather, unroll 8 (reps: idempotent diagnostic repeat) ----------
__global__ __launch_bounds__(256, 8) void gather_bf16(const uint4* __restrict__ xb,
                                                      uint4* __restrict__ ob,
                                                      const int* __restrict__ rowptr,
                                                      const unsigned short* __restrict__ col,
                                                      int reps) {
    int t = threadIdx.x;
    int grp = t >> 4;
    int half = (t >> 3) & 1;
    int ln8 = t & 7;
    int node = blockIdx.x * 16 + grp;   // grid exactly covers 50000
    for (int rep = 0; rep < reps; ++rep) {
        int beg = rowptr[node], end = rowptr[node + 1];
        int cnt = end - beg;
        int ch = (cnt - half + 1) >> 1;
        const unsigned short* cp = col + beg + half;
        float a[8];
        if (half == 0) {
            uint4 v = xb[(size_t)node * 8 + ln8];
            a[0] = bflo(v.x); a[1] = bfhi(v.x); a[2] = bflo(v.y); a[3] = bfhi(v.y);
            a[4] = bflo(v.z); a[5] = bfhi(v.z); a[6] = bflo(v.w); a[7] = bfhi(v.w);
        } else {
#pragma unroll
            for (int i = 0; i < 8; ++i) a[i] = 0.0f;
        }
        gather_rows(xb, cp, ch, ln8, a);
#pragma unroll
        for (int j = 0; j < 8; ++j) a[j] += __shfl_xor(a[j], 8);
        if (half == 0) {
            uint4 o;
            o.x = f2bf(a[0]) | (f2bf(a[1]) << 16);
            o.y = f2bf(a[2]) | (f2bf(a[3]) << 16);
            o.z = f2bf(a[4]) | (f2bf(a[5]) << 16);
            o.w = f2bf(a[6]) | (f2bf(a[7]) << 16);
            ob[(size_t)node * 8 + ln8] = o;
        }
        __asm__ volatile("" ::: "memory");   // defeat cross-rep CSE; reps are value-identical
    }
}

// ---------- fused: y = relu( (x + gather(x)) @ W^T + b ) -- MFMA MLP (reps: diagnostic) ----------
__global__ __launch_bounds__(256, 6) void gather_linear(const uint4* __restrict__ xb,
                                                        unsigned short* __restrict__ y,
                                                        const int* __restrict__ rowptr,
                                                        const unsigned short* __restrict__ col,
                                                        const float* __restrict__ W,
                                                        const float* __restrict__ b,
                                                        int reps) {
    __shared__ __align__(16) unsigned short hlb[16 * 72];       // h bf16, stride 72 (conflict-free)
    __shared__ __align__(16) unsigned short Wb[4 * 2 * 64 * 8]; // B-frags [wave][kk][lane][8]
    int t = threadIdx.x;
    int wv = t >> 6, lane = t & 63;
    int lo16 = lane & 15, hi4 = lane >> 4;
    int grp = t >> 4;
    int half = (t >> 3) & 1;
    int ln8 = t & 7;
    int node = blockIdx.x * 16 + grp;   // grid exactly covers 50000

    for (int rep = 0; rep < reps; ++rep) {
        // ---- B-fragment precompute: Wb[wv][kk][lane][j] = W[wv*16+lo16][kk*32+hi4*8+j] ----
        {
            const float* wp = W + (wv * 16 + lo16) * 64 + hi4 * 8;
#pragma unroll
            for (int kk = 0; kk < 2; ++kk) {
                float4 w0 = *(const float4*)(wp + kk * 32);
                float4 w1 = *(const float4*)(wp + kk * 32 + 4);
                uint4 pk;
                pk.x = f2bf(w0.x) | (f2bf(w0.y) << 16);
                pk.y = f2bf(w0.z) | (f2bf(w0.w) << 16);
                pk.z = f2bf(w1.x) | (f2bf(w1.y) << 16);
                pk.w = f2bf(w1.z) | (f2bf(w1.w) << 16);
                *(uint4*)&Wb[((wv * 2 + kk) * 64 + lane) * 8] = pk;
            }
        }

        // ---- gather phase: h = x + sum_{j in N} x_j ----
        int beg = rowptr[node], end = rowptr[node + 1];
        int cnt = end - beg;
        int ch = (cnt - half + 1) >> 1;
        const unsigned short* cp = col + beg + half;
        float a[8];
        if (half == 0) {
            uint4 v = xb[(size_t)node * 8 + ln8];
            a[0] = bflo(v.x); a[1] = bfhi(v.x); a[2] = bflo(v.y); a[3] = bfhi(v.y);
            a[4] = bflo(v.z); a[5] = bfhi(v.z); a[6] = bflo(v.w); a[7] = bfhi(v.w);
        } else {
#pragma unroll
            for (int i = 0; i < 8; ++i) a[i] = 0.0f;
        }
        gather_rows(xb, cp, ch, ln8, a);
#pragma unroll
        for (int j = 0; j < 8; ++j) a[j] += __shfl_xor(a[j], 8);
        if (half == 0) {
            uint4 o4;
            o4.x = f2bf(a[0]) | (f2bf(a[1]) << 16);
            o4.y = f2bf(a[2]) | (f2bf(a[3]) << 16);
            o4.z = f2bf(a[4]) | (f2bf(a[5]) << 16);
            o4.w = f2bf(a[6]) | (f2bf(a[7]) << 16);
            *(uint4*)&hlb[grp * 72 + ln8 * 8] = o4;   // 16B, conflict-free (stride 72)
        }
        __syncthreads();

        // ---- MFMA MLP: 2 x mfma_f32_16x16x32_bf16 per wave ----
        f32x4 acc = {0.0f, 0.0f, 0.0f, 0.0f};
        bf16x8 a0 = *(const bf16x8*)&hlb[lo16 * 72 + hi4 * 8];
        bf16x8 a1 = *(const bf16x8*)&hlb[lo16 * 72 + 32 + hi4 * 8];
        bf16x8 b0 = *(const bf16x8*)&Wb[((wv * 2 + 0) * 64 + lane) * 8];
        bf16x8 b1 = *(const bf16x8*)&Wb[((wv * 2 + 1) * 64 + lane) * 8];
        acc = __builtin_amdgcn_mfma_f32_16x16x32_bf16(a0, b0, acc, 0, 0, 0);
        acc = __builtin_amdgcn_mfma_f32_16x16x32_bf16(a1, b1, acc, 0, 0, 0);

        int o = wv * 16 + lo16;
        float bo = b[o];
        size_t nbase = (size_t)blockIdx.x * 16;
#pragma unroll
        for (int r = 0; r < 4; ++r) {
            int nr = hi4 * 4 + r;
            y[(nbase + nr) * 64 + o] = (unsigned short)f2bf(fmaxf(acc[r] + bo, 0.0f));
        }
        __syncthreads();                     // protect hlb/Wb reuse across reps
        __asm__ volatile("" ::: "memory");   // defeat cross-rep CSE; reps are value-identical
    }
}

// ---------- pool: batch sorted -> contiguous segments ----------
__device__ __forceinline__ int lower_bound_dev(const int* __restrict__ a, int n, int v) {
    int lo = 0, hi = n;
    while (lo < hi) { int mid = (lo + hi) >> 1; if (a[mid] < v) lo = mid + 1; else hi = mid; }
    return lo;
}

__global__ __launch_bounds__(256) void pool_seg_bf16(const unsigned short* __restrict__ xb,
                                                     const int* __restrict__ batch,
                                                     float* __restrict__ out) {
    int g = blockIdx.x;
    int lo = lower_bound_dev(batch, N_NODES, g);
    int hi = lower_bound_dev(batch, N_NODES, g + 1);
    int lane = threadIdx.x & 63;
    int sub = threadIdx.x >> 6;
    float acc = 0.0f;
    for (int n = lo + sub; n < hi; n += 4)
        acc += __uint_as_float(((unsigned)xb[(size_t)n * 64 + lane]) << 16);
    __shared__ float red[256];
    red[threadIdx.x] = acc;
    __syncthreads();
    if (sub == 0)
        out[(size_t)g * D + lane] = red[lane] + red[64 + lane] + red[128 + lane] + red[192 + lane];
}

// ---------- host ----------
extern "C" void kernel_launch(void* const* d_in, const int* in_sizes, int n_in,
                              void* d_out, int out_size, void* d_ws, size_t ws_size,
                              hipStream_t stream) {
    const float* x_in  = (const float*)d_in[0];
    const int*   ei    = (const int*)d_in[1];
    const int*   eei   = (const int*)d_in[2];
    const int*   batch = (const int*)d_in[3];
    const float* Ws    = (const float*)d_in[4];
    const float* bs    = (const float*)d_in[5];
    float* out = (float*)d_out;

    unsigned short* A = (unsigned short*)d_ws;          // y (bf16) [N*D]
    unsigned short* B = A + (size_t)N_NODES * D;        // x / x' (bf16)
    unsigned short* colAll = B + (size_t)N_NODES * D;   // u16 col [E_ALL]
    unsigned* pairs = (unsigned*)(colAll + E_ALL);      // u32 pairs [E_ALL]
    int* p = (int*)(pairs + E_ALL);
    int* rowptr = p;        p += N_ALL + 1;
    int* bucketTotal = p;   p += NBUCK;
    int* bucketBase = p;    p += NBUCK + 1;
    int* bucketCursor = p;  p += NBUCK;

    const int* e_src = ei;
    const int* e_dst = ei + N_EDGES;
    const int* x_src = eei;
    const int* x_dst = eei + N_EDGES;

    dim3 blk(256);

    // input fp32 -> bf16 (into B); also zeroes bucketTotal (replaces memset dispatch)
    const int cgrid = (N_NODES * D / 8 + 255) / 256;   // 1563
    x_to_bf16<<<cgrid, blk, 0, stream>>>((const float4*)x_in, (uint4*)B, bucketTotal);

    // CSR build: bucket totals -> scan -> bucketed u32-pair sort -> per-bucket rowptr+col
    bucket_count<<<BC_BLOCKS, blk, 0, stream>>>(e_dst, x_dst, bucketTotal);
    bucket_scan<<<1, blk, 0, stream>>>(bucketTotal, bucketBase, bucketCursor);
    bin_scatter<<<NCHUNK, blk, 0, stream>>>(e_src, e_dst, x_src, x_dst, bucketCursor, pairs);
    bucket_place<<<NBUCK, blk, 0, stream>>>(pairs, bucketBase, rowptr, colAll);

    const int lgrid = N_NODES / 16;            // 3125, exact

    // all 4 layers uniform bf16; layer 0's two kernels run reps=5 (idempotent) so they
    // cross the rocprof top-5 visibility threshold and yield per-kernel counters.
    for (int i = 0; i < NUM_LAYERS; ++i) {
        int reps = (i == 0) ? 5 : 1;
        gather_linear<<<lgrid, blk, 0, stream>>>((const uint4*)B, A,
                                                 rowptr, colAll,
                                                 Ws + (size_t)i * D * D,
                                                 bs + (size_t)i * D, reps);
        gather_bf16<<<lgrid, blk, 0, stream>>>((const uint4*)A, (uint4*)B,
                                               rowptr + N_NODES, colAll, reps);
    }

    pool_seg_bf16<<<NUM_GRAPHS, blk, 0, stream>>>(B, batch, out);
}

// Round 6
// 411.033 us; speedup vs baseline: 1.0470x; 1.0470x over previous
//
#include <hip/hip_runtime.h>

#define N_NODES 50000
#define N_EDGES 800000
#define D 64
#define NUM_LAYERS 4
#define NUM_GRAPHS 128
#define N_ALL (2 * N_NODES)
#define E_ALL (2 * N_EDGES)
#define BSHIFT 9
#define NBUCK ((N_ALL + 511) / 512)     // 196 buckets of 512 dst ids
#define CHUNK 3072                      // edges per bin_scatter block (12/thread)
#define NCHUNK ((E_ALL + CHUNK - 1) / CHUNK)  // 521
#define REPS_CSR 5                      // diagnostic repeat count for CSR kernels

typedef __attribute__((ext_vector_type(8))) short bf16x8;   // 8 bf16 (4 VGPRs)
typedef __attribute__((ext_vector_type(4))) float f32x4;    // MFMA accumulator

// ---------- bf16 helpers (RNE pack, shift unpack) ----------
__device__ __forceinline__ unsigned f2bf(float f) {
    unsigned u = __float_as_uint(f);
    return (u + 0x7FFFu + ((u >> 16) & 1u)) >> 16;
}
__device__ __forceinline__ float bflo(unsigned p) { return __uint_as_float(p << 16); }
__device__ __forceinline__ float bfhi(unsigned p) { return __uint_as_float(p & 0xFFFF0000u); }
__device__ __forceinline__ void acc8(float* a, uint4 v) {
    a[0] += bflo(v.x); a[1] += bfhi(v.x);
    a[2] += bflo(v.y); a[3] += bfhi(v.y);
    a[4] += bflo(v.z); a[5] += bfhi(v.z);
    a[6] += bflo(v.w); a[7] += bfhi(v.w);
}

// ---------- pre-pass: x fp32 -> bf16 (also zeroes the 5 bucketTotal banks) ----------
__global__ __launch_bounds__(256) void x_to_bf16(const float4* __restrict__ xf,
                                                 uint4* __restrict__ xb,
                                                 int* __restrict__ bucketTotal) {
    int t = threadIdx.x;
    if (blockIdx.x == 0)
        for (int j = t; j < NBUCK * REPS_CSR; j += 256) bucketTotal[j] = 0;
    int idx = blockIdx.x * 256 + t;          // one uint4 (8 bf16) per thread
    if (idx < N_NODES * D / 8) {
        float4 v0 = xf[(size_t)idx * 2];
        float4 v1 = xf[(size_t)idx * 2 + 1];
        uint4 o;
        o.x = f2bf(v0.x) | (f2bf(v0.y) << 16);
        o.y = f2bf(v0.z) | (f2bf(v0.w) << 16);
        o.z = f2bf(v1.x) | (f2bf(v1.y) << 16);
        o.w = f2bf(v1.z) | (f2bf(v1.w) << 16);
        xb[idx] = o;
    }
}

// ---------- pass 0: coarse bucket totals (reps: each rep accumulates into its own bank) ----------
#define BC_BLOCKS 256
__global__ __launch_bounds__(256) void bucket_count(const int* __restrict__ dR,
                                                    const int* __restrict__ dX,
                                                    int* __restrict__ bucketTotalBanks,
                                                    int reps) {
    __shared__ int lc[NBUCK];
    int t = threadIdx.x;
    for (int rep = 0; rep < reps; ++rep) {
        for (int j = t; j < NBUCK; j += 256) lc[j] = 0;
        __syncthreads();
        for (int e = blockIdx.x * 256 + t; e < N_EDGES; e += BC_BLOCKS * 256) {
            atomicAdd(&lc[dR[e] >> BSHIFT], 1);
            atomicAdd(&lc[(N_NODES + dX[e]) >> BSHIFT], 1);
        }
        __syncthreads();
        int* bt = bucketTotalBanks + rep * NBUCK;
        for (int j = t; j < NBUCK; j += 256) {
            int v = lc[j];
            if (v) atomicAdd(&bt[j], v);
        }
        __syncthreads();
    }
}

// ---------- pass 0b: scan bank-0 totals; init all 5 cursor banks ----------
__global__ __launch_bounds__(256) void bucket_scan(const int* __restrict__ bucketTotal,
                                                   int* __restrict__ bucketBase,
                                                   int* __restrict__ bucketCursor) {
    __shared__ int s[256];
    int t = threadIdx.x;
    int v = (t < NBUCK) ? bucketTotal[t] : 0;
    s[t] = v;
    __syncthreads();
    for (int off = 1; off < 256; off <<= 1) {
        int tv = (t >= off) ? s[t - off] : 0;
        __syncthreads();
        s[t] += tv;
        __syncthreads();
    }
    if (t < NBUCK) {
        int excl = s[t] - v;
        bucketBase[t] = excl;
        for (int k = 0; k < REPS_CSR; ++k) bucketCursor[k * NBUCK + t] = excl;
    }
    if (t == NBUCK - 1) bucketBase[NBUCK] = s[t];   // == E_ALL
}

// ---------- pass 1: bin u32 pairs by bucket (reps: bank-per-rep cursors; only last rep
// writes the real pairs array, earlier reps write scratch -> race-free across blocks) ----------
__global__ __launch_bounds__(256) void bin_scatter(const int* __restrict__ sR,
                                                   const int* __restrict__ dR,
                                                   const int* __restrict__ sX,
                                                   const int* __restrict__ dX,
                                                   int* __restrict__ bucketCursorBanks,
                                                   unsigned* __restrict__ pairs,
                                                   unsigned* __restrict__ pairsScratch,
                                                   int reps) {
    __shared__ unsigned lpair[CHUNK];
    __shared__ unsigned char lbuck[CHUNK];
    __shared__ int lcnt[NBUCK];
    __shared__ int lbase[NBUCK];
    __shared__ int gbase[NBUCK];
    __shared__ int sc[256];
    __shared__ int tot;
    int t = threadIdx.x;
    int base = blockIdx.x * CHUNK;

    for (int rep = 0; rep < reps; ++rep) {
        for (int j = t; j < NBUCK; j += 256) lcnt[j] = 0;
        __syncthreads();

        unsigned myp[12];
        int myr[12], myb[12];
#pragma unroll
        for (int i = 0; i < 12; ++i) {
            int e = base + i * 256 + t;
            if (e < E_ALL) {
                bool isR = (e < N_EDGES);
                int d = isR ? dR[e] : (N_NODES + dX[e - N_EDGES]);
                int s = isR ? sR[e] : sX[e - N_EDGES];
                myp[i] = ((unsigned)(d & 511) << 16) | (unsigned)s;
                myb[i] = d >> BSHIFT;
                myr[i] = atomicAdd(&lcnt[myb[i]], 1);
            }
        }
        __syncthreads();

        int v = (t < NBUCK) ? lcnt[t] : 0;
        sc[t] = v;
        __syncthreads();
        for (int off = 1; off < 256; off <<= 1) {
            int tv = (t >= off) ? sc[t - off] : 0;
            __syncthreads();
            sc[t] += tv;
            __syncthreads();
        }
        if (t < NBUCK) {
            lbase[t] = sc[t] - v;
            if (v > 0) gbase[t] = atomicAdd(&bucketCursorBanks[rep * NBUCK + t], v);
        }
        if (t == NBUCK - 1) tot = sc[t];
        __syncthreads();

#pragma unroll
        for (int i = 0; i < 12; ++i) {
            int e = base + i * 256 + t;
            if (e < E_ALL) {
                int p = lbase[myb[i]] + myr[i];
                lpair[p] = myp[i];
                lbuck[p] = (unsigned char)myb[i];
            }
        }
        __syncthreads();

        unsigned* outp = (rep == reps - 1) ? pairs : pairsScratch;
        int total = tot;
        for (int j = t; j < total; j += 256) {
            int b = lbuck[j];
            outp[(size_t)gbase[b] + (j - lbase[b])] = lpair[j];
        }
        __syncthreads();
    }
}

// ---------- pass 2: per bucket rowptr+col (reps: fully idempotent, block owns bucket) ----------
__global__ __launch_bounds__(256) void bucket_place(const unsigned* __restrict__ pairs,
                                                    const int* __restrict__ bucketBase,
                                                    int* __restrict__ rowptr,
                                                    unsigned short* __restrict__ col,
                                                    int reps) {
    __shared__ unsigned short scol[10240];
    __shared__ int ldeg[512];
    __shared__ int lcur[512];
    __shared__ int s1[256];
    int b = blockIdx.x;
    int d0 = b << BSHIFT;
    int nd = min(512, N_ALL - d0);
    int t = threadIdx.x;
    int base = bucketBase[b];
    int cnt = bucketBase[b + 1] - base;

    for (int rep = 0; rep < reps; ++rep) {
        ldeg[t] = 0; ldeg[t + 256] = 0;
        __syncthreads();
        for (int i = t; i < cnt; i += 256) {
            int dl = pairs[(size_t)base + i] >> 16;
            atomicAdd(&ldeg[dl], 1);
        }
        __syncthreads();
        int v0 = ldeg[2 * t], v1 = ldeg[2 * t + 1];
        int pv = v0 + v1;
        s1[t] = pv;
        __syncthreads();
        for (int off = 1; off < 256; off <<= 1) {
            int tv = (t >= off) ? s1[t - off] : 0;
            __syncthreads();
            s1[t] += tv;
            __syncthreads();
        }
        int before = s1[t] - pv;
        lcur[2 * t] = before;
        lcur[2 * t + 1] = before + v0;
        if (2 * t < nd)     rowptr[d0 + 2 * t]     = base + before;
        if (2 * t + 1 < nd) rowptr[d0 + 2 * t + 1] = base + before + v0;
        if (b == NBUCK - 1 && t == 0) rowptr[N_ALL] = base + cnt;
        __syncthreads();
        for (int i = t; i < cnt; i += 256) {
            unsigned pr = pairs[(size_t)base + i];
            int dl = pr >> 16;
            int p = atomicAdd(&lcur[dl], 1);
            scol[p] = (unsigned short)(pr & 0xFFFFu);
        }
        __syncthreads();
        for (int i = t; i < cnt; i += 256) col[base + i] = scol[i];
        __syncthreads();
    }
}

// ---------- shared gather helper: a[8] += sum of neighbor rows (split-edge, unroll 8) ----------
__device__ __forceinline__ void gather_rows(const uint4* __restrict__ xb,
                                            const unsigned short* __restrict__ cp,
                                            int ch, int ln8, float* a) {
    int i = 0;
    for (; i + 8 <= ch; i += 8) {
        int s0 = cp[2 * i],      s1 = cp[2 * i + 2],  s2 = cp[2 * i + 4],  s3 = cp[2 * i + 6];
        int s4 = cp[2 * i + 8],  s5 = cp[2 * i + 10], s6 = cp[2 * i + 12], s7 = cp[2 * i + 14];
        uint4 v0 = xb[(size_t)s0 * 8 + ln8];
        uint4 v1 = xb[(size_t)s1 * 8 + ln8];
        uint4 v2 = xb[(size_t)s2 * 8 + ln8];
        uint4 v3 = xb[(size_t)s3 * 8 + ln8];
        uint4 v4 = xb[(size_t)s4 * 8 + ln8];
        uint4 v5 = xb[(size_t)s5 * 8 + ln8];
        uint4 v6 = xb[(size_t)s6 * 8 + ln8];
        uint4 v7 = xb[(size_t)s7 * 8 + ln8];
        acc8(a, v0); acc8(a, v1); acc8(a, v2); acc8(a, v3);
        acc8(a, v4); acc8(a, v5); acc8(a, v6); acc8(a, v7);
    }
    for (; i + 4 <= ch; i += 4) {
        int s0 = cp[2 * i], s1 = cp[2 * i + 2], s2 = cp[2 * i + 4], s3 = cp[2 * i + 6];
        uint4 v0 = xb[(size_t)s0 * 8 + ln8];
        uint4 v1 = xb[(size_t)s1 * 8 + ln8];
        uint4 v2 = xb[(size_t)s2 * 8 + ln8];
        uint4 v3 = xb[(size_t)s3 * 8 + ln8];
        acc8(a, v0); acc8(a, v1); acc8(a, v2); acc8(a, v3);
    }
    for (; i < ch; ++i) acc8(a, xb[(size_t)cp[2 * i] * 8 + ln8]);
}

// ---------- split-edge bf16 gather, unroll 8 ----------
__global__ __launch_bounds__(256, 8) void gather_bf16(const uint4* __restrict__ xb,
                                                      uint4* __restrict__ ob,
                                                      const int* __restrict__ rowptr,
                                                      const unsigned short* __restrict__ col) {
    int t = threadIdx.x;
    int grp = t >> 4;
    int half = (t >> 3) & 1;
    int ln8 = t & 7;
    int node = blockIdx.x * 16 + grp;   // grid exactly covers 50000
    int beg = rowptr[node], end = rowptr[node + 1];
    int cnt = end - beg;
    int ch = (cnt - half + 1) >> 1;
    const unsigned short* cp = col + beg + half;
    float a[8];
    if (half == 0) {
        uint4 v = xb[(size_t)node * 8 + ln8];
        a[0] = bflo(v.x); a[1] = bfhi(v.x); a[2] = bflo(v.y); a[3] = bfhi(v.y);
        a[4] = bflo(v.z); a[5] = bfhi(v.z); a[6] = bflo(v.w); a[7] = bfhi(v.w);
    } else {
#pragma unroll
        for (int i = 0; i < 8; ++i) a[i] = 0.0f;
    }
    gather_rows(xb, cp, ch, ln8, a);
#pragma unroll
    for (int j = 0; j < 8; ++j) a[j] += __shfl_xor(a[j], 8);
    if (half == 0) {
        uint4 o;
        o.x = f2bf(a[0]) | (f2bf(a[1]) << 16);
        o.y = f2bf(a[2]) | (f2bf(a[3]) << 16);
        o.z = f2bf(a[4]) | (f2bf(a[5]) << 16);
        o.w = f2bf(a[6]) | (f2bf(a[7]) << 16);
        ob[(size_t)node * 8 + ln8] = o;
    }
}

// ---------- fused: y = relu( (x + gather(x)) @ W^T + b ) -- MFMA MLP ----------
__global__ __launch_bounds__(256, 6) void gather_linear(const uint4* __restrict__ xb,
                                                        unsigned short* __restrict__ y,
                                                        const int* __restrict__ rowptr,
                                                        const unsigned short* __restrict__ col,
                                                        const float* __restrict__ W,
                                                        const float* __restrict__ b) {
    __shared__ __align__(16) unsigned short hlb[16 * 72];       // h bf16, stride 72 (conflict-free)
    __shared__ __align__(16) unsigned short Wb[4 * 2 * 64 * 8]; // B-frags [wave][kk][lane][8]
    int t = threadIdx.x;
    int wv = t >> 6, lane = t & 63;
    int lo16 = lane & 15, hi4 = lane >> 4;

    // ---- B-fragment precompute: Wb[wv][kk][lane][j] = W[wv*16+lo16][kk*32+hi4*8+j] ----
    {
        const float* wp = W + (wv * 16 + lo16) * 64 + hi4 * 8;
#pragma unroll
        for (int kk = 0; kk < 2; ++kk) {
            float4 w0 = *(const float4*)(wp + kk * 32);
            float4 w1 = *(const float4*)(wp + kk * 32 + 4);
            uint4 pk;
            pk.x = f2bf(w0.x) | (f2bf(w0.y) << 16);
            pk.y = f2bf(w0.z) | (f2bf(w0.w) << 16);
            pk.z = f2bf(w1.x) | (f2bf(w1.y) << 16);
            pk.w = f2bf(w1.z) | (f2bf(w1.w) << 16);
            *(uint4*)&Wb[((wv * 2 + kk) * 64 + lane) * 8] = pk;
        }
    }

    // ---- gather phase: h = x + sum_{j in N} x_j ----
    int grp = t >> 4;
    int half = (t >> 3) & 1;
    int ln8 = t & 7;
    int node = blockIdx.x * 16 + grp;   // grid exactly covers 50000
    int beg = rowptr[node], end = rowptr[node + 1];
    int cnt = end - beg;
    int ch = (cnt - half + 1) >> 1;
    const unsigned short* cp = col + beg + half;
    float a[8];
    if (half == 0) {
        uint4 v = xb[(size_t)node * 8 + ln8];
        a[0] = bflo(v.x); a[1] = bfhi(v.x); a[2] = bflo(v.y); a[3] = bfhi(v.y);
        a[4] = bflo(v.z); a[5] = bfhi(v.z); a[6] = bflo(v.w); a[7] = bfhi(v.w);
    } else {
#pragma unroll
        for (int i = 0; i < 8; ++i) a[i] = 0.0f;
    }
    gather_rows(xb, cp, ch, ln8, a);
#pragma unroll
    for (int j = 0; j < 8; ++j) a[j] += __shfl_xor(a[j], 8);
    if (half == 0) {
        uint4 o4;
        o4.x = f2bf(a[0]) | (f2bf(a[1]) << 16);
        o4.y = f2bf(a[2]) | (f2bf(a[3]) << 16);
        o4.z = f2bf(a[4]) | (f2bf(a[5]) << 16);
        o4.w = f2bf(a[6]) | (f2bf(a[7]) << 16);
        *(uint4*)&hlb[grp * 72 + ln8 * 8] = o4;   // 16B, conflict-free (stride 72)
    }
    __syncthreads();

    // ---- MFMA MLP: 2 x mfma_f32_16x16x32_bf16 per wave ----
    f32x4 acc = {0.0f, 0.0f, 0.0f, 0.0f};
    bf16x8 a0 = *(const bf16x8*)&hlb[lo16 * 72 + hi4 * 8];
    bf16x8 a1 = *(const bf16x8*)&hlb[lo16 * 72 + 32 + hi4 * 8];
    bf16x8 b0 = *(const bf16x8*)&Wb[((wv * 2 + 0) * 64 + lane) * 8];
    bf16x8 b1 = *(const bf16x8*)&Wb[((wv * 2 + 1) * 64 + lane) * 8];
    acc = __builtin_amdgcn_mfma_f32_16x16x32_bf16(a0, b0, acc, 0, 0, 0);
    acc = __builtin_amdgcn_mfma_f32_16x16x32_bf16(a1, b1, acc, 0, 0, 0);

    int o = wv * 16 + lo16;
    float bo = b[o];
    size_t nbase = (size_t)blockIdx.x * 16;
#pragma unroll
    for (int r = 0; r < 4; ++r) {
        int nr = hi4 * 4 + r;
        y[(nbase + nr) * 64 + o] = (unsigned short)f2bf(fmaxf(acc[r] + bo, 0.0f));
    }
}

// ---------- pool: batch sorted -> contiguous segments ----------
__device__ __forceinline__ int lower_bound_dev(const int* __restrict__ a, int n, int v) {
    int lo = 0, hi = n;
    while (lo < hi) { int mid = (lo + hi) >> 1; if (a[mid] < v) lo = mid + 1; else hi = mid; }
    return lo;
}

__global__ __launch_bounds__(256) void pool_seg_bf16(const unsigned short* __restrict__ xb,
                                                     const int* __restrict__ batch,
                                                     float* __restrict__ out) {
    int g = blockIdx.x;
    int lo = lower_bound_dev(batch, N_NODES, g);
    int hi = lower_bound_dev(batch, N_NODES, g + 1);
    int lane = threadIdx.x & 63;
    int sub = threadIdx.x >> 6;
    float acc = 0.0f;
    for (int n = lo + sub; n < hi; n += 4)
        acc += __uint_as_float(((unsigned)xb[(size_t)n * 64 + lane]) << 16);
    __shared__ float red[256];
    red[threadIdx.x] = acc;
    __syncthreads();
    if (sub == 0)
        out[(size_t)g * D + lane] = red[lane] + red[64 + lane] + red[128 + lane] + red[192 + lane];
}

// ---------- host ----------
extern "C" void kernel_launch(void* const* d_in, const int* in_sizes, int n_in,
                              void* d_out, int out_size, void* d_ws, size_t ws_size,
                              hipStream_t stream) {
    const float* x_in  = (const float*)d_in[0];
    const int*   ei    = (const int*)d_in[1];
    const int*   eei   = (const int*)d_in[2];
    const int*   batch = (const int*)d_in[3];
    const float* Ws    = (const float*)d_in[4];
    const float* bs    = (const float*)d_in[5];
    float* out = (float*)d_out;

    unsigned short* A = (unsigned short*)d_ws;          // y (bf16) [N*D]
    unsigned short* B = A + (size_t)N_NODES * D;        // x / x' (bf16)
    unsigned short* colAll = B + (size_t)N_NODES * D;   // u16 col [E_ALL]
    unsigned* pairs = (unsigned*)(colAll + E_ALL);      // u32 pairs [E_ALL]
    unsigned* pairsScratch = pairs + E_ALL;             // u32 scratch [E_ALL] (probe reps)
    int* p = (int*)(pairsScratch + E_ALL);
    int* rowptr = p;        p += N_ALL + 1;
    int* bucketTotal = p;   p += NBUCK * REPS_CSR;      // 5 banks
    int* bucketBase = p;    p += NBUCK + 1;
    int* bucketCursor = p;  p += NBUCK * REPS_CSR;      // 5 banks

    const int* e_src = ei;
    const int* e_dst = ei + N_EDGES;
    const int* x_src = eei;
    const int* x_dst = eei + N_EDGES;

    dim3 blk(256);

    // input fp32 -> bf16 (into B); also zeroes the 5 bucketTotal banks
    const int cgrid = (N_NODES * D / 8 + 255) / 256;   // 1563
    x_to_bf16<<<cgrid, blk, 0, stream>>>((const float4*)x_in, (uint4*)B, bucketTotal);

    // CSR build (bucket_count / bin_scatter / bucket_place run REPS_CSR idempotent reps
    // so they cross the rocprof top-5 threshold and surface per-kernel counters)
    bucket_count<<<BC_BLOCKS, blk, 0, stream>>>(e_dst, x_dst, bucketTotal, REPS_CSR);
    bucket_scan<<<1, blk, 0, stream>>>(bucketTotal, bucketBase, bucketCursor);
    bin_scatter<<<NCHUNK, blk, 0, stream>>>(e_src, e_dst, x_src, x_dst, bucketCursor,
                                            pairs, pairsScratch, REPS_CSR);
    bucket_place<<<NBUCK, blk, 0, stream>>>(pairs, bucketBase, rowptr, colAll, REPS_CSR);

    const int lgrid = N_NODES / 16;            // 3125, exact

    // all 4 layers uniform bf16: gather_linear(B->A) then expander gather_bf16(A->B)
    for (int i = 0; i < NUM_LAYERS; ++i) {
        gather_linear<<<lgrid, blk, 0, stream>>>((const uint4*)B, A,
                                                 rowptr, colAll,
                                                 Ws + (size_t)i * D * D,
                                                 bs + (size_t)i * D);
        gather_bf16<<<lgrid, blk, 0, stream>>>((const uint4*)A, (uint4*)B,
                                               rowptr + N_NODES, colAll);
    }

    pool_seg_bf16<<<NUM_GRAPHS, blk, 0, stream>>>(B, batch, out);
}

// Round 7
// 256.023 us; speedup vs baseline: 1.6809x; 1.6055x over previous
//
#include <hip/hip_runtime.h>

#define N_NODES 50000
#define N_EDGES 800000
#define D 64
#define NUM_LAYERS 4
#define NUM_GRAPHS 128
#define N_ALL (2 * N_NODES)
#define E_ALL (2 * N_EDGES)
#define BSHIFT 9
#define NBUCK ((N_ALL + 511) / 512)     // 196 buckets of 512 dst ids
#define CHUNK 3072                      // edges per bin_scatter block (12/thread)
#define NCHUNK ((E_ALL + CHUNK - 1) / CHUNK)  // 521
#define CAP 12288                       // fixed slots per bucket (expected max ~8.6k)

typedef __attribute__((ext_vector_type(8))) short bf16x8;   // 8 bf16 (4 VGPRs)
typedef __attribute__((ext_vector_type(4))) float f32x4;    // MFMA accumulator

// ---------- bf16 helpers (RNE pack, shift unpack) ----------
__device__ __forceinline__ unsigned f2bf(float f) {
    unsigned u = __float_as_uint(f);
    return (u + 0x7FFFu + ((u >> 16) & 1u)) >> 16;
}
__device__ __forceinline__ float bflo(unsigned p) { return __uint_as_float(p << 16); }
__device__ __forceinline__ float bfhi(unsigned p) { return __uint_as_float(p & 0xFFFF0000u); }
__device__ __forceinline__ void acc8(float* a, uint4 v) {
    a[0] += bflo(v.x); a[1] += bfhi(v.x);
    a[2] += bflo(v.y); a[3] += bfhi(v.y);
    a[4] += bflo(v.z); a[5] += bfhi(v.z);
    a[6] += bflo(v.w); a[7] += bfhi(v.w);
}

// ---------- pre-pass: x fp32 -> bf16; init bucket cursors; zero pooled output ----------
__global__ __launch_bounds__(256) void x_to_bf16(const float4* __restrict__ xf,
                                                 uint4* __restrict__ xb,
                                                 int* __restrict__ cursor,
                                                 float* __restrict__ out) {
    int t = threadIdx.x;
    if (blockIdx.x == 0 && t < NBUCK) cursor[t] = t * CAP;
    if (blockIdx.x == 1)
        for (int j = t; j < NUM_GRAPHS * D; j += 256) out[j] = 0.0f;
    int idx = blockIdx.x * 256 + t;          // one uint4 (8 bf16) per thread
    if (idx < N_NODES * D / 8) {
        float4 v0 = xf[(size_t)idx * 2];
        float4 v1 = xf[(size_t)idx * 2 + 1];
        uint4 o;
        o.x = f2bf(v0.x) | (f2bf(v0.y) << 16);
        o.y = f2bf(v0.z) | (f2bf(v0.w) << 16);
        o.z = f2bf(v1.x) | (f2bf(v1.y) << 16);
        o.w = f2bf(v1.z) | (f2bf(v1.w) << 16);
        xb[idx] = o;
    }
}

// ---------- pass 1: bin u32 pairs (d_low9<<16 | src16) into fixed-cap bucket regions ----------
__global__ __launch_bounds__(256) void bin_scatter(const int* __restrict__ sR,
                                                   const int* __restrict__ dR,
                                                   const int* __restrict__ sX,
                                                   const int* __restrict__ dX,
                                                   int* __restrict__ cursor,
                                                   unsigned* __restrict__ pairs) {
    __shared__ unsigned lpair[CHUNK];
    __shared__ unsigned char lbuck[CHUNK];
    __shared__ int lcnt[NBUCK];
    __shared__ int lbase[NBUCK];
    __shared__ int gbase[NBUCK];
    __shared__ int sc[256];
    __shared__ int tot;
    int t = threadIdx.x;
    for (int j = t; j < NBUCK; j += 256) lcnt[j] = 0;
    __syncthreads();

    int base = blockIdx.x * CHUNK;
    unsigned myp[12];
    int myr[12], myb[12];
#pragma unroll
    for (int i = 0; i < 12; ++i) {
        int e = base + i * 256 + t;
        if (e < E_ALL) {
            bool isR = (e < N_EDGES);
            int d = isR ? dR[e] : (N_NODES + dX[e - N_EDGES]);
            int s = isR ? sR[e] : sX[e - N_EDGES];
            myp[i] = ((unsigned)(d & 511) << 16) | (unsigned)s;
            myb[i] = d >> BSHIFT;
            myr[i] = atomicAdd(&lcnt[myb[i]], 1);
        }
    }
    __syncthreads();

    int v = (t < NBUCK) ? lcnt[t] : 0;
    sc[t] = v;
    __syncthreads();
    for (int off = 1; off < 256; off <<= 1) {
        int tv = (t >= off) ? sc[t - off] : 0;
        __syncthreads();
        sc[t] += tv;
        __syncthreads();
    }
    if (t < NBUCK) {
        lbase[t] = sc[t] - v;
        if (v > 0) gbase[t] = atomicAdd(&cursor[t], v);
    }
    if (t == NBUCK - 1) tot = sc[t];
    __syncthreads();

#pragma unroll
    for (int i = 0; i < 12; ++i) {
        int e = base + i * 256 + t;
        if (e < E_ALL) {
            int p = lbase[myb[i]] + myr[i];
            lpair[p] = myp[i];
            lbuck[p] = (unsigned char)myb[i];
        }
    }
    __syncthreads();

    int total = tot;
    for (int j = t; j < total; j += 256) {
        int b = lbuck[j];
        pairs[(size_t)gbase[b] + (j - lbase[b])] = lpair[j];
    }
}

// ---------- pass 2: per bucket -- degrees in LDS, beg/end arrays, place col ----------
__global__ __launch_bounds__(256) void bucket_place(const unsigned* __restrict__ pairs,
                                                    const int* __restrict__ cursor,
                                                    int* __restrict__ begA,
                                                    int* __restrict__ endA,
                                                    unsigned short* __restrict__ col) {
    __shared__ unsigned short scol[CAP];
    __shared__ int ldeg[512];
    __shared__ int lcur[512];
    __shared__ int s1[256];
    int b = blockIdx.x;
    int d0 = b << BSHIFT;
    int nd = min(512, N_ALL - d0);
    int t = threadIdx.x;
    int base = b * CAP;
    int cnt = cursor[b] - base;
    ldeg[t] = 0; ldeg[t + 256] = 0;
    __syncthreads();
    for (int i = t; i < cnt; i += 256) {
        int dl = pairs[(size_t)base + i] >> 16;
        atomicAdd(&ldeg[dl], 1);
    }
    __syncthreads();
    int v0 = ldeg[2 * t], v1 = ldeg[2 * t + 1];
    int pv = v0 + v1;
    s1[t] = pv;
    __syncthreads();
    for (int off = 1; off < 256; off <<= 1) {
        int tv = (t >= off) ? s1[t - off] : 0;
        __syncthreads();
        s1[t] += tv;
        __syncthreads();
    }
    int before = s1[t] - pv;
    lcur[2 * t] = before;
    lcur[2 * t + 1] = before + v0;
    if (2 * t < nd) {
        begA[d0 + 2 * t] = base + before;
        endA[d0 + 2 * t] = base + before + v0;
    }
    if (2 * t + 1 < nd) {
        begA[d0 + 2 * t + 1] = base + before + v0;
        endA[d0 + 2 * t + 1] = base + before + v0 + v1;
    }
    __syncthreads();
    for (int i = t; i < cnt; i += 256) {
        unsigned pr = pairs[(size_t)base + i];
        int dl = pr >> 16;
        int p = atomicAdd(&lcur[dl], 1);
        scol[p] = (unsigned short)(pr & 0xFFFFu);
    }
    __syncthreads();
    for (int i = t; i < cnt; i += 256) col[base + i] = scol[i];
}

// ---------- shared gather helper: a[8] += sum of neighbor rows (split-edge, unroll 8) ----------
__device__ __forceinline__ void gather_rows(const uint4* __restrict__ xb,
                                            const unsigned short* __restrict__ cp,
                                            int ch, int ln8, float* a) {
    int i = 0;
    for (; i + 8 <= ch; i += 8) {
        int s0 = cp[2 * i],      s1 = cp[2 * i + 2],  s2 = cp[2 * i + 4],  s3 = cp[2 * i + 6];
        int s4 = cp[2 * i + 8],  s5 = cp[2 * i + 10], s6 = cp[2 * i + 12], s7 = cp[2 * i + 14];
        uint4 v0 = xb[(size_t)s0 * 8 + ln8];
        uint4 v1 = xb[(size_t)s1 * 8 + ln8];
        uint4 v2 = xb[(size_t)s2 * 8 + ln8];
        uint4 v3 = xb[(size_t)s3 * 8 + ln8];
        uint4 v4 = xb[(size_t)s4 * 8 + ln8];
        uint4 v5 = xb[(size_t)s5 * 8 + ln8];
        uint4 v6 = xb[(size_t)s6 * 8 + ln8];
        uint4 v7 = xb[(size_t)s7 * 8 + ln8];
        acc8(a, v0); acc8(a, v1); acc8(a, v2); acc8(a, v3);
        acc8(a, v4); acc8(a, v5); acc8(a, v6); acc8(a, v7);
    }
    for (; i + 4 <= ch; i += 4) {
        int s0 = cp[2 * i], s1 = cp[2 * i + 2], s2 = cp[2 * i + 4], s3 = cp[2 * i + 6];
        uint4 v0 = xb[(size_t)s0 * 8 + ln8];
        uint4 v1 = xb[(size_t)s1 * 8 + ln8];
        uint4 v2 = xb[(size_t)s2 * 8 + ln8];
        uint4 v3 = xb[(size_t)s3 * 8 + ln8];
        acc8(a, v0); acc8(a, v1); acc8(a, v2); acc8(a, v3);
    }
    for (; i < ch; ++i) acc8(a, xb[(size_t)cp[2 * i] * 8 + ln8]);
}

// ---------- split-edge bf16 gather (expander layers 0..2) ----------
__global__ __launch_bounds__(256, 8) void gather_bf16(const uint4* __restrict__ xb,
                                                      uint4* __restrict__ ob,
                                                      const int* __restrict__ begA,
                                                      const int* __restrict__ endA,
                                                      const unsigned short* __restrict__ col) {
    int t = threadIdx.x;
    int grp = t >> 4;
    int half = (t >> 3) & 1;
    int ln8 = t & 7;
    int node = blockIdx.x * 16 + grp;   // grid exactly covers 50000
    int beg = begA[node], end = endA[node];
    int cnt = end - beg;
    int ch = (cnt - half + 1) >> 1;
    const unsigned short* cp = col + beg + half;
    float a[8];
    if (half == 0) {
        uint4 v = xb[(size_t)node * 8 + ln8];
        a[0] = bflo(v.x); a[1] = bfhi(v.x); a[2] = bflo(v.y); a[3] = bfhi(v.y);
        a[4] = bflo(v.z); a[5] = bfhi(v.z); a[6] = bflo(v.w); a[7] = bfhi(v.w);
    } else {
#pragma unroll
        for (int i = 0; i < 8; ++i) a[i] = 0.0f;
    }
    gather_rows(xb, cp, ch, ln8, a);
#pragma unroll
    for (int j = 0; j < 8; ++j) a[j] += __shfl_xor(a[j], 8);
    if (half == 0) {
        uint4 o;
        o.x = f2bf(a[0]) | (f2bf(a[1]) << 16);
        o.y = f2bf(a[2]) | (f2bf(a[3]) << 16);
        o.z = f2bf(a[4]) | (f2bf(a[5]) << 16);
        o.w = f2bf(a[6]) | (f2bf(a[7]) << 16);
        ob[(size_t)node * 8 + ln8] = o;
    }
}

// ---------- last expander gather fused with graph pooling (batch is sorted) ----------
__global__ __launch_bounds__(256, 8) void gather_pool_bf16(const uint4* __restrict__ xb,
                                                           const int* __restrict__ begA,
                                                           const int* __restrict__ endA,
                                                           const unsigned short* __restrict__ col,
                                                           const int* __restrict__ batch,
                                                           float* __restrict__ out) {
    __shared__ float sacc[16 * 64];
    int t = threadIdx.x;
    int grp = t >> 4;
    int half = (t >> 3) & 1;
    int ln8 = t & 7;
    int nbase = blockIdx.x * 16;
    int node = nbase + grp;
    int beg = begA[node], end = endA[node];
    int cnt = end - beg;
    int ch = (cnt - half + 1) >> 1;
    const unsigned short* cp = col + beg + half;
    float a[8];
    if (half == 0) {
        uint4 v = xb[(size_t)node * 8 + ln8];
        a[0] = bflo(v.x); a[1] = bfhi(v.x); a[2] = bflo(v.y); a[3] = bfhi(v.y);
        a[4] = bflo(v.z); a[5] = bfhi(v.z); a[6] = bflo(v.w); a[7] = bfhi(v.w);
    } else {
#pragma unroll
        for (int i = 0; i < 8; ++i) a[i] = 0.0f;
    }
    gather_rows(xb, cp, ch, ln8, a);
#pragma unroll
    for (int j = 0; j < 8; ++j) a[j] += __shfl_xor(a[j], 8);
    if (half == 0) {
        float4* sp = (float4*)(sacc + grp * 64 + ln8 * 8);
        sp[0] = make_float4(a[0], a[1], a[2], a[3]);
        sp[1] = make_float4(a[4], a[5], a[6], a[7]);
    }
    __syncthreads();

    // per-graph run-length reduce over the block's 16 rows, then atomics (<=2-3 per col)
    if (t < 64) {
        int gprev = batch[nbase];
        float acc = 0.0f;
        for (int r = 0; r < 16; ++r) {
            int g = batch[nbase + r];
            float v = sacc[r * 64 + t];
            if (g != gprev) {
                atomicAdd(&out[(size_t)gprev * D + t], acc);
                acc = 0.0f;
                gprev = g;
            }
            acc += v;
        }
        atomicAdd(&out[(size_t)gprev * D + t], acc);
    }
}

// ---------- fused: y = relu( (x + gather(x)) @ W^T + b ) -- MFMA MLP ----------
__global__ __launch_bounds__(256, 6) void gather_linear(const uint4* __restrict__ xb,
                                                        unsigned short* __restrict__ y,
                                                        const int* __restrict__ begA,
                                                        const int* __restrict__ endA,
                                                        const unsigned short* __restrict__ col,
                                                        const float* __restrict__ W,
                                                        const float* __restrict__ b) {
    __shared__ __align__(16) unsigned short hlb[16 * 72];       // h bf16, stride 72 (conflict-free)
    __shared__ __align__(16) unsigned short Wb[4 * 2 * 64 * 8]; // B-frags [wave][kk][lane][8]
    int t = threadIdx.x;
    int wv = t >> 6, lane = t & 63;
    int lo16 = lane & 15, hi4 = lane >> 4;

    // ---- B-fragment precompute: Wb[wv][kk][lane][j] = W[wv*16+lo16][kk*32+hi4*8+j] ----
    {
        const float* wp = W + (wv * 16 + lo16) * 64 + hi4 * 8;
#pragma unroll
        for (int kk = 0; kk < 2; ++kk) {
            float4 w0 = *(const float4*)(wp + kk * 32);
            float4 w1 = *(const float4*)(wp + kk * 32 + 4);
            uint4 pk;
            pk.x = f2bf(w0.x) | (f2bf(w0.y) << 16);
            pk.y = f2bf(w0.z) | (f2bf(w0.w) << 16);
            pk.z = f2bf(w1.x) | (f2bf(w1.y) << 16);
            pk.w = f2bf(w1.z) | (f2bf(w1.w) << 16);
            *(uint4*)&Wb[((wv * 2 + kk) * 64 + lane) * 8] = pk;
        }
    }

    // ---- gather phase: h = x + sum_{j in N} x_j ----
    int grp = t >> 4;
    int half = (t >> 3) & 1;
    int ln8 = t & 7;
    int node = blockIdx.x * 16 + grp;   // grid exactly covers 50000
    int beg = begA[node], end = endA[node];
    int cnt = end - beg;
    int ch = (cnt - half + 1) >> 1;
    const unsigned short* cp = col + beg + half;
    float a[8];
    if (half == 0) {
        uint4 v = xb[(size_t)node * 8 + ln8];
        a[0] = bflo(v.x); a[1] = bfhi(v.x); a[2] = bflo(v.y); a[3] = bfhi(v.y);
        a[4] = bflo(v.z); a[5] = bfhi(v.z); a[6] = bflo(v.w); a[7] = bfhi(v.w);
    } else {
#pragma unroll
        for (int i = 0; i < 8; ++i) a[i] = 0.0f;
    }
    gather_rows(xb, cp, ch, ln8, a);
#pragma unroll
    for (int j = 0; j < 8; ++j) a[j] += __shfl_xor(a[j], 8);
    if (half == 0) {
        uint4 o4;
        o4.x = f2bf(a[0]) | (f2bf(a[1]) << 16);
        o4.y = f2bf(a[2]) | (f2bf(a[3]) << 16);
        o4.z = f2bf(a[4]) | (f2bf(a[5]) << 16);
        o4.w = f2bf(a[6]) | (f2bf(a[7]) << 16);
        *(uint4*)&hlb[grp * 72 + ln8 * 8] = o4;   // 16B, conflict-free (stride 72)
    }
    __syncthreads();

    // ---- MFMA MLP: 2 x mfma_f32_16x16x32_bf16 per wave ----
    f32x4 acc = {0.0f, 0.0f, 0.0f, 0.0f};
    bf16x8 a0 = *(const bf16x8*)&hlb[lo16 * 72 + hi4 * 8];
    bf16x8 a1 = *(const bf16x8*)&hlb[lo16 * 72 + 32 + hi4 * 8];
    bf16x8 b0 = *(const bf16x8*)&Wb[((wv * 2 + 0) * 64 + lane) * 8];
    bf16x8 b1 = *(const bf16x8*)&Wb[((wv * 2 + 1) * 64 + lane) * 8];
    acc = __builtin_amdgcn_mfma_f32_16x16x32_bf16(a0, b0, acc, 0, 0, 0);
    acc = __builtin_amdgcn_mfma_f32_16x16x32_bf16(a1, b1, acc, 0, 0, 0);

    int o = wv * 16 + lo16;
    float bo = b[o];
    size_t nbase = (size_t)blockIdx.x * 16;
#pragma unroll
    for (int r = 0; r < 4; ++r) {
        int nr = hi4 * 4 + r;
        y[(nbase + nr) * 64 + o] = (unsigned short)f2bf(fmaxf(acc[r] + bo, 0.0f));
    }
}

// ---------- host ----------
extern "C" void kernel_launch(void* const* d_in, const int* in_sizes, int n_in,
                              void* d_out, int out_size, void* d_ws, size_t ws_size,
                              hipStream_t stream) {
    const float* x_in  = (const float*)d_in[0];
    const int*   ei    = (const int*)d_in[1];
    const int*   eei   = (const int*)d_in[2];
    const int*   batch = (const int*)d_in[3];
    const float* Ws    = (const float*)d_in[4];
    const float* bs    = (const float*)d_in[5];
    float* out = (float*)d_out;

    unsigned short* A = (unsigned short*)d_ws;          // y (bf16) [N*D]
    unsigned short* B = A + (size_t)N_NODES * D;        // x / x' (bf16)
    unsigned short* colAll = B + (size_t)N_NODES * D;   // u16 col [NBUCK*CAP] (holed CSR)
    unsigned* pairs = (unsigned*)(colAll + (size_t)NBUCK * CAP);  // u32 [NBUCK*CAP]
    int* p = (int*)(pairs + (size_t)NBUCK * CAP);
    int* begA = p;          p += N_ALL;
    int* endA = p;          p += N_ALL;
    int* cursor = p;        p += NBUCK;

    const int* e_src = ei;
    const int* e_dst = ei + N_EDGES;
    const int* x_src = eei;
    const int* x_dst = eei + N_EDGES;

    dim3 blk(256);

    // input fp32 -> bf16 (into B); init bucket cursors; zero pooled out
    const int cgrid = (N_NODES * D / 8 + 255) / 256;   // 1563
    x_to_bf16<<<cgrid, blk, 0, stream>>>((const float4*)x_in, (uint4*)B, cursor, out);

    // CSR build: 2 kernels (fixed-cap buckets; no count/scan passes)
    bin_scatter<<<NCHUNK, blk, 0, stream>>>(e_src, e_dst, x_src, x_dst, cursor, pairs);
    bucket_place<<<NBUCK, blk, 0, stream>>>(pairs, cursor, begA, endA, colAll);

    const int lgrid = N_NODES / 16;            // 3125, exact

    // 4 layers; final expander gather fused with pooling
    for (int i = 0; i < NUM_LAYERS; ++i) {
        gather_linear<<<lgrid, blk, 0, stream>>>((const uint4*)B, A,
                                                 begA, endA, colAll,
                                                 Ws + (size_t)i * D * D,
                                                 bs + (size_t)i * D);
        if (i < NUM_LAYERS - 1)
            gather_bf16<<<lgrid, blk, 0, stream>>>((const uint4*)A, (uint4*)B,
                                                   begA + N_NODES, endA + N_NODES, colAll);
        else
            gather_pool_bf16<<<lgrid, blk, 0, stream>>>((const uint4*)A,
                                                        begA + N_NODES, endA + N_NODES,
                                                        colAll, batch, out);
    }
}